// Round 6
// baseline (454.010 us; speedup 1.0000x reference)
//
#include <hip/hip_runtime.h>

// out = noised + (2*STD) * noise, STD = 0.05  ->  out = a + 0.1f * b
// N = 64*3*512*512 = 50,331,648 fp32 (n4 = 12,582,912 float4s).
// Latency-limited at baseline (2.6 TB/s HBM, VALUBusy 1.6%): unroll x4
// (8 independent 16B loads in flight per thread) + nontemporal stores so
// the output stream doesn't evict the L3-resident second input.
// NOTE: __builtin_nontemporal_store needs clang ext_vector_type, not
// HIP_vector_type<float,4> -- hence fx4 below.

typedef float fx4 __attribute__((ext_vector_type(4)));

#define UNROLL 4

__global__ __launch_bounds__(256) void gaussian_noise_add_kernel(
    const fx4* __restrict__ a,
    const fx4* __restrict__ b,
    fx4* __restrict__ out,
    int n4)
{
    const int tb = 256;
    const int stride = gridDim.x * tb * UNROLL;
    int base = blockIdx.x * tb * UNROLL + threadIdx.x;

    for (int i = base; i < n4; i += stride) {
        const int i0 = i;
        const int i1 = i + tb;
        const int i2 = i + 2 * tb;
        const int i3 = i + 3 * tb;
        if (i3 < n4) {
            // Fast path: issue all 8 loads before any use.
            fx4 a0 = a[i0], a1 = a[i1], a2 = a[i2], a3 = a[i3];
            fx4 b0 = b[i0], b1 = b[i1], b2 = b[i2], b3 = b[i3];
            fx4 o0 = a0 + 0.1f * b0;
            fx4 o1 = a1 + 0.1f * b1;
            fx4 o2 = a2 + 0.1f * b2;
            fx4 o3 = a3 + 0.1f * b3;
            __builtin_nontemporal_store(o0, &out[i0]);
            __builtin_nontemporal_store(o1, &out[i1]);
            __builtin_nontemporal_store(o2, &out[i2]);
            __builtin_nontemporal_store(o3, &out[i3]);
        } else {
            // Remainder path (not taken for this problem size).
            if (i0 < n4) { fx4 o = a[i0] + 0.1f * b[i0]; __builtin_nontemporal_store(o, &out[i0]); }
            if (i1 < n4) { fx4 o = a[i1] + 0.1f * b[i1]; __builtin_nontemporal_store(o, &out[i1]); }
            if (i2 < n4) { fx4 o = a[i2] + 0.1f * b[i2]; __builtin_nontemporal_store(o, &out[i2]); }
        }
    }
}

// Scalar tail kernel (defensive; n is divisible by 4 for this problem).
__global__ void gaussian_noise_tail_kernel(
    const float* __restrict__ a,
    const float* __restrict__ b,
    float* __restrict__ out,
    int start, int n)
{
    int i = start + blockIdx.x * blockDim.x + threadIdx.x;
    if (i < n) out[i] = fmaf(0.1f, b[i], a[i]);
}

extern "C" void kernel_launch(void* const* d_in, const int* in_sizes, int n_in,
                              void* d_out, int out_size, void* d_ws, size_t ws_size,
                              hipStream_t stream)
{
    const float* a = (const float*)d_in[0];   // noised
    const float* b = (const float*)d_in[1];   // noise
    float* out = (float*)d_out;
    int n = out_size;
    int n4 = n / 4;

    const int block = 256;
    // 2048 blocks = 8 WGs/CU on 256 CUs, grid-stride over the rest.
    int grid = (n4 + block * UNROLL - 1) / (block * UNROLL);
    if (grid > 2048) grid = 2048;
    if (grid > 0) {
        gaussian_noise_add_kernel<<<grid, block, 0, stream>>>(
            (const fx4*)a, (const fx4*)b, (fx4*)out, n4);
    }

    int tail_start = n4 * 4;
    int tail = n - tail_start;
    if (tail > 0) {
        gaussian_noise_tail_kernel<<<(tail + block - 1) / block, block, 0, stream>>>(
            a, b, out, tail_start, n);
    }
}

// Round 7
// 433.409 us; speedup vs baseline: 1.0475x; 1.0475x over previous
//
#include <hip/hip_runtime.h>

// out = noised + (2*STD) * noise, STD = 0.05  ->  out = a + 0.1f * b
// N = 64*3*512*512 = 50,331,648 fp32 (n4 = 12,582,912 float4s).
//
// R4 (grid-stride, plain stores): 154 us @ 2.6 TB/s EA. R5 (x4 unroll + nt
// stores): 172 us — WORSE (compiler re-serialized; VGPR=24 showed loads never
// stayed in flight; nt hurt the write stream). Revert both.
// This round: exact-cover launch, one float4 per thread, no loop — the m13
// copy-probe shape that hits 6.29 TB/s. Waves retire right after their store
// (no serial waitcnt chain across iterations); CP refills CUs continuously.

typedef float fx4 __attribute__((ext_vector_type(4)));

__global__ __launch_bounds__(256) void gaussian_noise_add_kernel(
    const fx4* __restrict__ a,
    const fx4* __restrict__ b,
    fx4* __restrict__ out,
    int n4)
{
    int i = blockIdx.x * blockDim.x + threadIdx.x;
    if (i < n4) {
        fx4 va = a[i];
        fx4 vb = b[i];
        out[i] = va + 0.1f * vb;
    }
}

// Scalar tail kernel (defensive; n is divisible by 4 for this problem).
__global__ void gaussian_noise_tail_kernel(
    const float* __restrict__ a,
    const float* __restrict__ b,
    float* __restrict__ out,
    int start, int n)
{
    int i = start + blockIdx.x * blockDim.x + threadIdx.x;
    if (i < n) out[i] = fmaf(0.1f, b[i], a[i]);
}

extern "C" void kernel_launch(void* const* d_in, const int* in_sizes, int n_in,
                              void* d_out, int out_size, void* d_ws, size_t ws_size,
                              hipStream_t stream)
{
    const float* a = (const float*)d_in[0];   // noised
    const float* b = (const float*)d_in[1];   // noise
    float* out = (float*)d_out;
    int n = out_size;
    int n4 = n / 4;

    const int block = 256;
    // Exact cover: one float4 per thread. n4 = 12,582,912 -> 49,152 blocks.
    int grid = (n4 + block - 1) / block;
    if (grid > 0) {
        gaussian_noise_add_kernel<<<grid, block, 0, stream>>>(
            (const fx4*)a, (const fx4*)b, (fx4*)out, n4);
    }

    int tail_start = n4 * 4;
    int tail = n - tail_start;
    if (tail > 0) {
        gaussian_noise_tail_kernel<<<(tail + block - 1) / block, block, 0, stream>>>(
            a, b, out, tail_start, n);
    }
}